// Round 3
// baseline (431.071 us; speedup 1.0000x reference)
//
#include <hip/hip_runtime.h>
#include <hip/hip_bf16.h>

#define KA 512
#define DD 1024
#define LMBDA_C 1000.0f
#define T_ITER 11

typedef short bf16x8 __attribute__((ext_vector_type(8)));   // 8 bf16 (4 VGPRs)
typedef float f32x4 __attribute__((ext_vector_type(4)));

__device__ __forceinline__ float bf2f(unsigned short v) {
  return __uint_as_float(((unsigned)v) << 16);
}

// round-to-nearest-even f32 -> bf16 (finite inputs only)
__device__ __forceinline__ unsigned short f2bf(float f) {
  unsigned u = __float_as_uint(f);
  u += 0x7fffu + ((u >> 16) & 1u);
  return (unsigned short)(u >> 16);
}

// ---------------------------------------------------------------------------
// Fused: dtype detect (scan 8192 16-bit words of input A; f32 data decodes to
// huge bf16-interpretations w.h.p., P(miss) ~ 0.52^8192 ~ 0) + eval convert
// + joint spectral max. One block of 512.
__global__ void k_prep(const void* Ain, const void* ea_in, const void* eb_in,
                       float* eaf, float* ebf, float* smax, float* maxbuf) {
  __shared__ float red[512];
  const int t = threadIdx.x;
  const ushort4* u4 = (const ushort4*)Ain;
  float m = 0.f;
  for (int i = t; i < 2048; i += 512) {            // 8192 words
    const ushort4 v = u4[i];
    float f0 = fabsf(bf2f(v.x)), f1 = fabsf(bf2f(v.y));
    float f2 = fabsf(bf2f(v.z)), f3 = fabsf(bf2f(v.w));
    if (!isnan(f0)) m = fmaxf(m, f0);
    if (!isnan(f1)) m = fmaxf(m, f1);
    if (!isnan(f2)) m = fmaxf(m, f2);
    if (!isnan(f3)) m = fmaxf(m, f3);
  }
  red[t] = m;
  __syncthreads();
  for (int s = 256; s > 0; s >>= 1) {
    if (t < s) red[t] = fmaxf(red[t], red[t + s]);
    __syncthreads();
  }
  const float mx = red[0];
  const bool isbf = (mx < 100.f);
  if (t == 0) maxbuf[0] = mx;
  __syncthreads();
  const float a = isbf ? bf2f(((const unsigned short*)ea_in)[t])
                       : ((const float*)ea_in)[t];
  const float b = isbf ? bf2f(((const unsigned short*)eb_in)[t])
                       : ((const float*)eb_in)[t];
  eaf[t] = a;
  ebf[t] = b;
  red[t] = fmaxf(a, b);
  __syncthreads();
  for (int s = 256; s > 0; s >>= 1) {
    if (t < s) red[t] = fmaxf(red[t], red[t + s]);
    __syncthreads();
  }
  if (t == 0) smax[0] = red[0];
}

// ---------------------------------------------------------------------------
// bf16 path: MFMA gram. G = L^T * Rm via mfma_f32_16x16x32_bf16 (bf16
// products are exact in f32 — numerically equivalent to the f32 gram modulo
// sum order). Verified layouts (m89/m120): A[m=lane&15][k=quad*8+j],
// B[k=quad*8+j][n=lane&15], D[row=quad*4+reg][col=lane&15].
// 64x64 tile/block, 4 waves; wave w owns rows w*16..w*16+16 (4 col-tiles).
// LDS: k-transposed tiles (row stride 40 shorts = 80 B: 16B-aligned b128
// frag reads, conflict-free; staging writes 2-way max).
// z=0: G_a=A^T A, z=1: G_b=B^T B, z=2: M=B^T A (R_bot = M^T read by k_pcg).
#define LTS 40
__global__ __launch_bounds__(256) void k_gram_mfma(const void* __restrict__ Av,
    const void* __restrict__ Bv, float* __restrict__ Gfin,
    const float* __restrict__ maxbuf) {
  if (maxbuf[0] >= 100.f) return;   // f32 data: handled by k_gram fallback
  __shared__ __align__(16) unsigned short Lt[64][LTS];
  __shared__ __align__(16) unsigned short Bt[64][LTS];
  const int z = blockIdx.z;
  const unsigned short *L, *Rm;
  int off;
  if (z == 0)      { L = (const unsigned short*)Av; Rm = L; off = 0; }
  else if (z == 1) { L = (const unsigned short*)Bv; Rm = L; off = 262144; }
  else             { L = (const unsigned short*)Bv;
                     Rm = (const unsigned short*)Av; off = 524288; }
  float* out = Gfin + off;
  const int r0 = blockIdx.y * 64, c0 = blockIdx.x * 64;
  const int t = threadIdx.x;
  const int lane = t & 63, w = t >> 6;
  const int quad = lane >> 4, l16 = lane & 15;
  // staging map: kk = t&31 (k-row in stage), mm = (t>>5)*8 (col group)
  const int kk = t & 31;
  const int mm = (t >> 5) * 8;

  f32x4 acc0 = {0.f, 0.f, 0.f, 0.f};
  f32x4 acc1 = acc0, acc2 = acc0, acc3 = acc0;

  for (int k0 = 0; k0 < DD; k0 += 32) {
    const ushort4 la = *(const ushort4*)(L + (k0 + kk) * KA + r0 + mm);
    const ushort4 lb = *(const ushort4*)(L + (k0 + kk) * KA + r0 + mm + 4);
    const ushort4 ra = *(const ushort4*)(Rm + (k0 + kk) * KA + c0 + mm);
    const ushort4 rb = *(const ushort4*)(Rm + (k0 + kk) * KA + c0 + mm + 4);
    __syncthreads();                 // previous stage's frag reads complete
    Lt[mm + 0][kk] = la.x; Lt[mm + 1][kk] = la.y;
    Lt[mm + 2][kk] = la.z; Lt[mm + 3][kk] = la.w;
    Lt[mm + 4][kk] = lb.x; Lt[mm + 5][kk] = lb.y;
    Lt[mm + 6][kk] = lb.z; Lt[mm + 7][kk] = lb.w;
    Bt[mm + 0][kk] = ra.x; Bt[mm + 1][kk] = ra.y;
    Bt[mm + 2][kk] = ra.z; Bt[mm + 3][kk] = ra.w;
    Bt[mm + 4][kk] = rb.x; Bt[mm + 5][kk] = rb.y;
    Bt[mm + 6][kk] = rb.z; Bt[mm + 7][kk] = rb.w;
    __syncthreads();
    const bf16x8 af = *(const bf16x8*)&Lt[w * 16 + l16][quad * 8];
    const bf16x8 bf0 = *(const bf16x8*)&Bt[ 0 + l16][quad * 8];
    const bf16x8 bf1 = *(const bf16x8*)&Bt[16 + l16][quad * 8];
    const bf16x8 bf2 = *(const bf16x8*)&Bt[32 + l16][quad * 8];
    const bf16x8 bf3 = *(const bf16x8*)&Bt[48 + l16][quad * 8];
    acc0 = __builtin_amdgcn_mfma_f32_16x16x32_bf16(af, bf0, acc0, 0, 0, 0);
    acc1 = __builtin_amdgcn_mfma_f32_16x16x32_bf16(af, bf1, acc1, 0, 0, 0);
    acc2 = __builtin_amdgcn_mfma_f32_16x16x32_bf16(af, bf2, acc2, 0, 0, 0);
    acc3 = __builtin_amdgcn_mfma_f32_16x16x32_bf16(af, bf3, acc3, 0, 0, 0);
  }
  const int orow = r0 + w * 16 + quad * 4;
#pragma unroll
  for (int r = 0; r < 4; ++r) {
    float* op = out + (orow + r) * KA + c0 + l16;
    op[0]  = acc0[r];
    op[16] = acc1[r];
    op[32] = acc2[r];
    op[48] = acc3[r];
  }
}

// ---------------------------------------------------------------------------
// f32 fallback path (predicated): R12-proven 64x64 tile, k-split x2.
// z=0: G_a, z=1: G_b, z=2: M=B^T A, z=3: A^T B (unused by pcg; harmless)
__global__ __launch_bounds__(256) void k_gram(const void* __restrict__ A,
    const void* __restrict__ B, float* __restrict__ Gfin,
    float* __restrict__ Gp0, const float* __restrict__ maxbuf) {
  if (maxbuf[0] < 100.f) return;    // bf16 data: handled by k_gram_mfma
  __shared__ float sL[16][68];
  __shared__ float sR[16][68];
  const int z2 = blockIdx.z;
  const int h = z2 & 1, z = z2 >> 1;
  const void *L, *Rm;
  int off;
  if (z == 0)      { L = A; Rm = A; off = 0; }
  else if (z == 1) { L = B; Rm = B; off = 262144; }
  else if (z == 2) { L = B; Rm = A; off = 524288; }
  else             { L = A; Rm = B; off = 786432; }
  float* out = (h ? Gfin : Gp0) + off;
  const int r0 = blockIdx.y * 64, c0 = blockIdx.x * 64;
  const int tx = threadIdx.x, ty = threadIdx.y;
  const int t = ty * 16 + tx;
  const int Ld = t >> 4;
  const int Lc = (t & 15) * 4;
  const int kbeg = h * 512;
  float acc[4][4] = {};
  for (int k0 = kbeg; k0 < kbeg + 512; k0 += 16) {
    *(float4*)&sL[Ld][Lc] = *(const float4*)((const float*)L +
                                             (k0 + Ld) * KA + r0 + Lc);
    *(float4*)&sR[Ld][Lc] = *(const float4*)((const float*)Rm +
                                             (k0 + Ld) * KA + c0 + Lc);
    __syncthreads();
#pragma unroll
    for (int d2 = 0; d2 < 16; ++d2) {
      const float4 av = *(const float4*)&sL[d2][ty * 4];
      const float4 bv = *(const float4*)&sR[d2][tx * 4];
      acc[0][0] = fmaf(av.x, bv.x, acc[0][0]); acc[0][1] = fmaf(av.x, bv.y, acc[0][1]);
      acc[0][2] = fmaf(av.x, bv.z, acc[0][2]); acc[0][3] = fmaf(av.x, bv.w, acc[0][3]);
      acc[1][0] = fmaf(av.y, bv.x, acc[1][0]); acc[1][1] = fmaf(av.y, bv.y, acc[1][1]);
      acc[1][2] = fmaf(av.y, bv.z, acc[1][2]); acc[1][3] = fmaf(av.y, bv.w, acc[1][3]);
      acc[2][0] = fmaf(av.z, bv.x, acc[2][0]); acc[2][1] = fmaf(av.z, bv.y, acc[2][1]);
      acc[2][2] = fmaf(av.z, bv.z, acc[2][2]); acc[2][3] = fmaf(av.z, bv.w, acc[2][3]);
      acc[3][0] = fmaf(av.w, bv.x, acc[3][0]); acc[3][1] = fmaf(av.w, bv.y, acc[3][1]);
      acc[3][2] = fmaf(av.w, bv.z, acc[3][2]); acc[3][3] = fmaf(av.w, bv.w, acc[3][3]);
    }
    __syncthreads();
  }
#pragma unroll
  for (int u = 0; u < 4; ++u) {
    const float4 o = make_float4(acc[u][0], acc[u][1], acc[u][2], acc[u][3]);
    *(float4*)(out + (r0 + ty * 4 + u) * KA + c0 + tx * 4) = o;
  }
}

// Gfin += Gp0 (f32 path only)
__global__ void k_combine(float* __restrict__ Gfin, const float* __restrict__ Gp0,
                          const float* __restrict__ maxbuf) {
  if (maxbuf[0] < 100.f) return;    // bf16 path: no partials
  const int i = blockIdx.x * 256 + threadIdx.x;
  float4* f4 = (float4*)Gfin;
  const float4 a = f4[i], b = ((const float4*)Gp0)[i];
  f4[i] = make_float4(a.x + b.x, a.y + b.y, a.z + b.z, a.w + b.w);
}

// ---------------------------------------------------------------------------
// Split G_a|G_b (first 524288 floats of Gfin) into bf16 hi+lo for the MFMA
// matvec in k_pcg. |g - hi - lo| <= 2^-17 |g|. Runs on BOTH dtype paths.
// Output into the (dead after k_combine) Gp0 region:
//   pack[0      .. 524287] = Ghi  ([Ghi_a | Ghi_b])
//   pack[524288 .. 1048575] = Glo
__global__ __launch_bounds__(256) void k_repack(const float* __restrict__ G,
    unsigned short* __restrict__ P) {
  const int i = blockIdx.x * 256 + threadIdx.x;   // 131072 threads x float4
  const float4 g = ((const float4*)G)[i];
  ushort4 h, l;
  h.x = f2bf(g.x); l.x = f2bf(g.x - bf2f(h.x));
  h.y = f2bf(g.y); l.y = f2bf(g.y - bf2f(h.y));
  h.z = f2bf(g.z); l.z = f2bf(g.z - bf2f(h.z));
  h.w = f2bf(g.w); l.w = f2bf(g.w - bf2f(h.w));
  ((ushort4*)P)[i] = h;
  ((ushort4*)(P + 524288))[i] = l;
}

// ---------------------------------------------------------------------------
// Whole PCG loop fused; matvec on the MFMA pipe with ALL 16 B-columns live:
// 16 systems per block, 64 blocks. G packed bf16 hi+lo (k_repack), p split
// bf16 hi+lo per iteration; 3 cross terms -> ~2e-5 relative matvec error
// (PCG truncation at T_ITER=11 is ~1e-3, so f32-grade for this solve).
// Per-system state (r,x,p,z) lives in registers: system s = tid>>5, its 32
// lanes own 16 elements each (4 strided float4s). Dot-product reductions are
// 5x shfl_xor inside the 32-lane group — no LDS, no barrier. Exactly two
// __syncthreads per iteration (q_s handoff, pbh handoff).
// MFMA mapping per wave wv: A row-tiles at wv*64 + {0,16,32,48} (+l16),
// A[m=l16][k=quad*8+j] = G[row][k]; B[k][n=l16] = p_{sys n}[k] from pbh/pbl;
// D[row=quad*4+reg][col=l16] -> q_s[sys][row].
#define PBS 520      // p-buffer row stride in shorts (1040 B, 16B-aligned)
#define QSS 524      // q_s row stride in floats (2096 B, 16B-aligned, %32=12)
__global__ __launch_bounds__(512, 2) void k_pcg(
    const float* __restrict__ G_a, const float* __restrict__ G_b,
    const float* __restrict__ M, const unsigned short* __restrict__ Gpk,
    const float* __restrict__ ea, const float* __restrict__ eb,
    const float* __restrict__ smax, const float* __restrict__ maxbuf,
    void* __restrict__ out) {
  __shared__ __align__(16) float q_s[16][QSS];
  __shared__ __align__(16) unsigned short pbh[16 * PBS];
  __shared__ __align__(16) unsigned short pbl[16 * PBS];

  const int tid = threadIdx.x;
  const int b = blockIdx.x;           // 0..63
  const int rb = b * 16;              // global system base row
  const int dir = rb >> 9;
  const float* __restrict__ G = dir ? G_b : G_a;
  const unsigned short* __restrict__ Gh = Gpk + dir * 262144;
  const unsigned short* __restrict__ Gl = Gpk + 524288 + dir * 262144;

  const int lane = tid & 63, wv = tid >> 6;
  const int quad = lane >> 4, l16 = lane & 15;
  const int kq = quad * 8;
  const int rA = wv * 64 + l16;       // A-frag base row (G row index)

  const int s = tid >> 5;             // system 0..15 (epilogue role)
  const int l = tid & 31;             // lane within system group
  const int rowl = (rb + s) & (KA - 1);

  const float sm = smax[0];
  const float e1 = (dir ? ea[rowl] : eb[rowl]) / sm;
  const float q1 = 1.f / (e1 * e1 + 1.f);
  const float p1i = e1 * q1;

  float4 w4[4], di4[4], r4[4], x4[4], p4[4], z4[4];
  const float* __restrict__ e2p = dir ? eb : ea;
  float rho = 0.f;
#pragma unroll
  for (int j = 0; j < 4; ++j) {
    const int c = l * 4 + 128 * j;
    const float4 e2 = *(const float4*)(e2p + c);
    const float vx = e2.x / sm, vy = e2.y / sm, vz = e2.z / sm, vw = e2.w / sm;
    const float qx = 1.f / (vx * vx + 1.f), qy = 1.f / (vy * vy + 1.f);
    const float qz = 1.f / (vz * vz + 1.f), qw = 1.f / (vw * vw + 1.f);
    float dre, dim;
    dre = p1i - vx * qx; dim = q1 - qx; w4[j].x = LMBDA_C * (dre * dre + dim * dim);
    dre = p1i - vy * qy; dim = q1 - qy; w4[j].y = LMBDA_C * (dre * dre + dim * dim);
    dre = p1i - vz * qz; dim = q1 - qz; w4[j].z = LMBDA_C * (dre * dre + dim * dim);
    dre = p1i - vw * qw; dim = q1 - qw; w4[j].w = LMBDA_C * (dre * dre + dim * dim);
    di4[j].x = 1.f / (G[(c + 0) * KA + c + 0] + w4[j].x);
    di4[j].y = 1.f / (G[(c + 1) * KA + c + 1] + w4[j].y);
    di4[j].z = 1.f / (G[(c + 2) * KA + c + 2] + w4[j].z);
    di4[j].w = 1.f / (G[(c + 3) * KA + c + 3] + w4[j].w);
    if (dir == 0) {
      r4[j] = *(const float4*)(M + rowl * KA + c);
    } else {                    // rhs = (B^T A)^T: gather M column rowl
      r4[j].x = M[(c + 0) * KA + rowl];
      r4[j].y = M[(c + 1) * KA + rowl];
      r4[j].z = M[(c + 2) * KA + rowl];
      r4[j].w = M[(c + 3) * KA + rowl];
    }
    x4[j] = make_float4(0.f, 0.f, 0.f, 0.f);
    const float4 z = make_float4(r4[j].x * di4[j].x, r4[j].y * di4[j].y,
                                 r4[j].z * di4[j].z, r4[j].w * di4[j].w);
    p4[j] = z;
    rho += r4[j].x * z.x + r4[j].y * z.y + r4[j].z * z.z + r4[j].w * z.w;
    ushort4 h4, l4;
    h4.x = f2bf(z.x); l4.x = f2bf(z.x - bf2f(h4.x));
    h4.y = f2bf(z.y); l4.y = f2bf(z.y - bf2f(h4.y));
    h4.z = f2bf(z.z); l4.z = f2bf(z.z - bf2f(h4.z));
    h4.w = f2bf(z.w); l4.w = f2bf(z.w - bf2f(h4.w));
    *(ushort4*)&pbh[s * PBS + c] = h4;
    *(ushort4*)&pbl[s * PBS + c] = l4;
  }
#pragma unroll
  for (int off = 16; off > 0; off >>= 1) rho += __shfl_xor(rho, off, 64);
  __syncthreads();                    // pbh/pbl ready for first matvec

  for (int it = 0; it < T_ITER; ++it) {
    // --- MFMA matvec: q_s[sys][row] = sum_k G[row][k] p_sys[k]
    {
      f32x4 mac0 = {0.f, 0.f, 0.f, 0.f};
      f32x4 mac1 = mac0, mac2 = mac0, mac3 = mac0;
#pragma unroll 2
      for (int k0 = 0; k0 < KA; k0 += 32) {
        const bf16x8 bh = *(const bf16x8*)&pbh[l16 * PBS + k0 + kq];
        const bf16x8 bl = *(const bf16x8*)&pbl[l16 * PBS + k0 + kq];
        const bf16x8 ah0 = *(const bf16x8*)(Gh + (rA +  0) * KA + k0 + kq);
        const bf16x8 al0 = *(const bf16x8*)(Gl + (rA +  0) * KA + k0 + kq);
        const bf16x8 ah1 = *(const bf16x8*)(Gh + (rA + 16) * KA + k0 + kq);
        const bf16x8 al1 = *(const bf16x8*)(Gl + (rA + 16) * KA + k0 + kq);
        const bf16x8 ah2 = *(const bf16x8*)(Gh + (rA + 32) * KA + k0 + kq);
        const bf16x8 al2 = *(const bf16x8*)(Gl + (rA + 32) * KA + k0 + kq);
        const bf16x8 ah3 = *(const bf16x8*)(Gh + (rA + 48) * KA + k0 + kq);
        const bf16x8 al3 = *(const bf16x8*)(Gl + (rA + 48) * KA + k0 + kq);
        mac0 = __builtin_amdgcn_mfma_f32_16x16x32_bf16(ah0, bh, mac0, 0, 0, 0);
        mac0 = __builtin_amdgcn_mfma_f32_16x16x32_bf16(ah0, bl, mac0, 0, 0, 0);
        mac0 = __builtin_amdgcn_mfma_f32_16x16x32_bf16(al0, bh, mac0, 0, 0, 0);
        mac1 = __builtin_amdgcn_mfma_f32_16x16x32_bf16(ah1, bh, mac1, 0, 0, 0);
        mac1 = __builtin_amdgcn_mfma_f32_16x16x32_bf16(ah1, bl, mac1, 0, 0, 0);
        mac1 = __builtin_amdgcn_mfma_f32_16x16x32_bf16(al1, bh, mac1, 0, 0, 0);
        mac2 = __builtin_amdgcn_mfma_f32_16x16x32_bf16(ah2, bh, mac2, 0, 0, 0);
        mac2 = __builtin_amdgcn_mfma_f32_16x16x32_bf16(ah2, bl, mac2, 0, 0, 0);
        mac2 = __builtin_amdgcn_mfma_f32_16x16x32_bf16(al2, bh, mac2, 0, 0, 0);
        mac3 = __builtin_amdgcn_mfma_f32_16x16x32_bf16(ah3, bh, mac3, 0, 0, 0);
        mac3 = __builtin_amdgcn_mfma_f32_16x16x32_bf16(ah3, bl, mac3, 0, 0, 0);
        mac3 = __builtin_amdgcn_mfma_f32_16x16x32_bf16(al3, bh, mac3, 0, 0, 0);
      }
      const int jb = wv * 64 + quad * 4;
      *(f32x4*)&q_s[l16][jb +  0] = mac0;
      *(f32x4*)&q_s[l16][jb + 16] = mac1;
      *(f32x4*)&q_s[l16][jb + 32] = mac2;
      *(f32x4*)&q_s[l16][jb + 48] = mac3;
    }
    __syncthreads();
    // --- PCG epilogue: per-system scalar updates, 32-lane reductions
    float pq = 0.f;
    float4 qv[4];
#pragma unroll
    for (int j = 0; j < 4; ++j) {
      const int c = l * 4 + 128 * j;
      float4 q = *(const float4*)&q_s[s][c];
      q.x += w4[j].x * p4[j].x; q.y += w4[j].y * p4[j].y;
      q.z += w4[j].z * p4[j].z; q.w += w4[j].w * p4[j].w;
      qv[j] = q;
      pq += p4[j].x * q.x + p4[j].y * q.y + p4[j].z * q.z + p4[j].w * q.w;
    }
#pragma unroll
    for (int off = 16; off > 0; off >>= 1) pq += __shfl_xor(pq, off, 64);
    const float alpha = (pq != 0.f) ? (rho / pq) : 0.f;
    float rhon = 0.f;
#pragma unroll
    for (int j = 0; j < 4; ++j) {
      x4[j].x = fmaf(alpha, p4[j].x, x4[j].x);
      x4[j].y = fmaf(alpha, p4[j].y, x4[j].y);
      x4[j].z = fmaf(alpha, p4[j].z, x4[j].z);
      x4[j].w = fmaf(alpha, p4[j].w, x4[j].w);
      r4[j].x = fmaf(-alpha, qv[j].x, r4[j].x);
      r4[j].y = fmaf(-alpha, qv[j].y, r4[j].y);
      r4[j].z = fmaf(-alpha, qv[j].z, r4[j].z);
      r4[j].w = fmaf(-alpha, qv[j].w, r4[j].w);
      z4[j] = make_float4(r4[j].x * di4[j].x, r4[j].y * di4[j].y,
                          r4[j].z * di4[j].z, r4[j].w * di4[j].w);
      rhon += r4[j].x * z4[j].x + r4[j].y * z4[j].y +
              r4[j].z * z4[j].z + r4[j].w * z4[j].w;
    }
#pragma unroll
    for (int off = 16; off > 0; off >>= 1) rhon += __shfl_xor(rhon, off, 64);
    const float beta = (rho != 0.f) ? (rhon / rho) : 0.f;
    rho = rhon;
#pragma unroll
    for (int j = 0; j < 4; ++j) {
      const int c = l * 4 + 128 * j;
      float4 pn;
      pn.x = fmaf(beta, p4[j].x, z4[j].x);
      pn.y = fmaf(beta, p4[j].y, z4[j].y);
      pn.z = fmaf(beta, p4[j].z, z4[j].z);
      pn.w = fmaf(beta, p4[j].w, z4[j].w);
      p4[j] = pn;
      ushort4 h4, l4;
      h4.x = f2bf(pn.x); l4.x = f2bf(pn.x - bf2f(h4.x));
      h4.y = f2bf(pn.y); l4.y = f2bf(pn.y - bf2f(h4.y));
      h4.z = f2bf(pn.z); l4.z = f2bf(pn.z - bf2f(h4.z));
      h4.w = f2bf(pn.w); l4.w = f2bf(pn.w - bf2f(h4.w));
      *(ushort4*)&pbh[s * PBS + c] = h4;
      *(ushort4*)&pbl[s * PBS + c] = l4;
    }
    __syncthreads();                  // pbh/pbl + q_s handoff for next iter
  }

  const bool isbf = (maxbuf[0] < 100.f);
#pragma unroll
  for (int j = 0; j < 4; ++j) {
    const int c = l * 4 + 128 * j;
    const int o = (rb + s) * KA + c;
    if (isbf) {
      ushort4 ob;
      ob.x = f2bf(x4[j].x); ob.y = f2bf(x4[j].y);
      ob.z = f2bf(x4[j].z); ob.w = f2bf(x4[j].w);
      *(ushort4*)((unsigned short*)out + o) = ob;
    } else {
      *(float4*)((float*)out + o) = x4[j];
    }
  }
}

// ---------------------------------------------------------------------------
extern "C" void kernel_launch(void* const* d_in, const int* in_sizes, int n_in,
                              void* d_out, int out_size, void* d_ws, size_t ws_size,
                              hipStream_t stream) {
  const void* Ain = d_in[0];   // sdescr_a [1024,512]
  const void* Bin = d_in[1];   // sdescr_b [1024,512]
  const void* Ein_a = d_in[2]; // evals_a [512]
  const void* Ein_b = d_in[3]; // evals_b [512]

  float* ws = (float*)d_ws;
  float* Gfin  = ws;              // 1048576 = [G_a | G_b | M | (f32-path A^T B)]
  float* Gp0   = Gfin + 1048576;  // 1048576 (f32-path k-half partial; then packs)
  float* eaf   = Gp0 + 1048576;   // 512
  float* ebf   = eaf + 512;       // 512
  float* maxbuf= ebf + 512;       // 1
  float* smax  = maxbuf + 1;      // 1

  float* G_a = Gfin;
  float* G_b = Gfin + 262144;
  float* M   = Gfin + 524288;
  unsigned short* Gpk = (unsigned short*)Gp0;  // [Ghi_a|Ghi_b|Glo_a|Glo_b], 2MB

  k_prep<<<1, 512, 0, stream>>>(Ain, Ein_a, Ein_b, eaf, ebf, smax, maxbuf);
  k_gram_mfma<<<dim3(8, 8, 3), 256, 0, stream>>>(Ain, Bin, Gfin, maxbuf);
  k_gram<<<dim3(8, 8, 8), dim3(16, 16), 0, stream>>>(Ain, Bin, Gfin, Gp0, maxbuf);
  k_combine<<<1024, 256, 0, stream>>>(Gfin, Gp0, maxbuf);
  k_repack<<<512, 256, 0, stream>>>(Gfin, Gpk);
  k_pcg<<<64, 512, 0, stream>>>(G_a, G_b, M, Gpk, eaf, ebf, smax, maxbuf, d_out);
}

// Round 5
// 419.737 us; speedup vs baseline: 1.0270x; 1.0270x over previous
//
#include <hip/hip_runtime.h>
#include <hip/hip_bf16.h>

#define KA 512
#define DD 1024
#define LMBDA_C 1000.0f
#define T_ITER 11

typedef short bf16x8 __attribute__((ext_vector_type(8)));   // 8 bf16 (4 VGPRs)
typedef float f32x4 __attribute__((ext_vector_type(4)));

__device__ __forceinline__ float bf2f(unsigned short v) {
  return __uint_as_float(((unsigned)v) << 16);
}

// round-to-nearest-even f32 -> bf16 (finite inputs only)
__device__ __forceinline__ unsigned short f2bf(float f) {
  unsigned u = __float_as_uint(f);
  u += 0x7fffu + ((u >> 16) & 1u);
  return (unsigned short)(u >> 16);
}

// ---------------------------------------------------------------------------
// Fused: dtype detect (scan 8192 16-bit words of input A; f32 data decodes to
// huge bf16-interpretations w.h.p., P(miss) ~ 0.52^8192 ~ 0) + eval convert
// + joint spectral max. One block of 512.
__global__ void k_prep(const void* Ain, const void* ea_in, const void* eb_in,
                       float* eaf, float* ebf, float* smax, float* maxbuf) {
  __shared__ float red[512];
  const int t = threadIdx.x;
  const ushort4* u4 = (const ushort4*)Ain;
  float m = 0.f;
  for (int i = t; i < 2048; i += 512) {            // 8192 words
    const ushort4 v = u4[i];
    float f0 = fabsf(bf2f(v.x)), f1 = fabsf(bf2f(v.y));
    float f2 = fabsf(bf2f(v.z)), f3 = fabsf(bf2f(v.w));
    if (!isnan(f0)) m = fmaxf(m, f0);
    if (!isnan(f1)) m = fmaxf(m, f1);
    if (!isnan(f2)) m = fmaxf(m, f2);
    if (!isnan(f3)) m = fmaxf(m, f3);
  }
  red[t] = m;
  __syncthreads();
  for (int s = 256; s > 0; s >>= 1) {
    if (t < s) red[t] = fmaxf(red[t], red[t + s]);
    __syncthreads();
  }
  const float mx = red[0];
  const bool isbf = (mx < 100.f);
  if (t == 0) maxbuf[0] = mx;
  __syncthreads();
  const float a = isbf ? bf2f(((const unsigned short*)ea_in)[t])
                       : ((const float*)ea_in)[t];
  const float b = isbf ? bf2f(((const unsigned short*)eb_in)[t])
                       : ((const float*)eb_in)[t];
  eaf[t] = a;
  ebf[t] = b;
  red[t] = fmaxf(a, b);
  __syncthreads();
  for (int s = 256; s > 0; s >>= 1) {
    if (t < s) red[t] = fmaxf(red[t], red[t + s]);
    __syncthreads();
  }
  if (t == 0) smax[0] = red[0];
}

// ---------------------------------------------------------------------------
// bf16 path: MFMA gram. G = L^T * Rm via mfma_f32_16x16x32_bf16 (bf16
// products are exact in f32 — numerically equivalent to the f32 gram modulo
// sum order). Verified layouts (m89/m120): A[m=lane&15][k=quad*8+j],
// B[k=quad*8+j][n=lane&15], D[row=quad*4+reg][col=lane&15].
// 64x64 tile/block, 4 waves; wave w owns rows w*16..w*16+16 (4 col-tiles).
// LDS: k-transposed tiles (row stride 40 shorts = 80 B: 16B-aligned b128
// frag reads, conflict-free; staging writes 2-way max).
// z=0: G_a=A^T A, z=1: G_b=B^T B, z=2: M=B^T A (R_bot = M^T read by k_pcg).
#define LTS 40
__global__ __launch_bounds__(256) void k_gram_mfma(const void* __restrict__ Av,
    const void* __restrict__ Bv, float* __restrict__ Gfin,
    const float* __restrict__ maxbuf) {
  if (maxbuf[0] >= 100.f) return;   // f32 data: handled by k_gram fallback
  __shared__ __align__(16) unsigned short Lt[64][LTS];
  __shared__ __align__(16) unsigned short Bt[64][LTS];
  const int z = blockIdx.z;
  const unsigned short *L, *Rm;
  int off;
  if (z == 0)      { L = (const unsigned short*)Av; Rm = L; off = 0; }
  else if (z == 1) { L = (const unsigned short*)Bv; Rm = L; off = 262144; }
  else             { L = (const unsigned short*)Bv;
                     Rm = (const unsigned short*)Av; off = 524288; }
  float* out = Gfin + off;
  const int r0 = blockIdx.y * 64, c0 = blockIdx.x * 64;
  const int t = threadIdx.x;
  const int lane = t & 63, w = t >> 6;
  const int quad = lane >> 4, l16 = lane & 15;
  // staging map: kk = t&31 (k-row in stage), mm = (t>>5)*8 (col group)
  const int kk = t & 31;
  const int mm = (t >> 5) * 8;

  f32x4 acc0 = {0.f, 0.f, 0.f, 0.f};
  f32x4 acc1 = acc0, acc2 = acc0, acc3 = acc0;

  for (int k0 = 0; k0 < DD; k0 += 32) {
    const ushort4 la = *(const ushort4*)(L + (k0 + kk) * KA + r0 + mm);
    const ushort4 lb = *(const ushort4*)(L + (k0 + kk) * KA + r0 + mm + 4);
    const ushort4 ra = *(const ushort4*)(Rm + (k0 + kk) * KA + c0 + mm);
    const ushort4 rb = *(const ushort4*)(Rm + (k0 + kk) * KA + c0 + mm + 4);
    __syncthreads();                 // previous stage's frag reads complete
    Lt[mm + 0][kk] = la.x; Lt[mm + 1][kk] = la.y;
    Lt[mm + 2][kk] = la.z; Lt[mm + 3][kk] = la.w;
    Lt[mm + 4][kk] = lb.x; Lt[mm + 5][kk] = lb.y;
    Lt[mm + 6][kk] = lb.z; Lt[mm + 7][kk] = lb.w;
    Bt[mm + 0][kk] = ra.x; Bt[mm + 1][kk] = ra.y;
    Bt[mm + 2][kk] = ra.z; Bt[mm + 3][kk] = ra.w;
    Bt[mm + 4][kk] = rb.x; Bt[mm + 5][kk] = rb.y;
    Bt[mm + 6][kk] = rb.z; Bt[mm + 7][kk] = rb.w;
    __syncthreads();
    const bf16x8 af = *(const bf16x8*)&Lt[w * 16 + l16][quad * 8];
    const bf16x8 bf0 = *(const bf16x8*)&Bt[ 0 + l16][quad * 8];
    const bf16x8 bf1 = *(const bf16x8*)&Bt[16 + l16][quad * 8];
    const bf16x8 bf2 = *(const bf16x8*)&Bt[32 + l16][quad * 8];
    const bf16x8 bf3 = *(const bf16x8*)&Bt[48 + l16][quad * 8];
    acc0 = __builtin_amdgcn_mfma_f32_16x16x32_bf16(af, bf0, acc0, 0, 0, 0);
    acc1 = __builtin_amdgcn_mfma_f32_16x16x32_bf16(af, bf1, acc1, 0, 0, 0);
    acc2 = __builtin_amdgcn_mfma_f32_16x16x32_bf16(af, bf2, acc2, 0, 0, 0);
    acc3 = __builtin_amdgcn_mfma_f32_16x16x32_bf16(af, bf3, acc3, 0, 0, 0);
  }
  const int orow = r0 + w * 16 + quad * 4;
#pragma unroll
  for (int r = 0; r < 4; ++r) {
    float* op = out + (orow + r) * KA + c0 + l16;
    op[0]  = acc0[r];
    op[16] = acc1[r];
    op[32] = acc2[r];
    op[48] = acc3[r];
  }
}

// ---------------------------------------------------------------------------
// f32 fallback path (predicated): R12-proven 64x64 tile, k-split x2.
// z=0: G_a, z=1: G_b, z=2: M=B^T A, z=3: A^T B (unused by pcg; harmless)
__global__ __launch_bounds__(256) void k_gram(const void* __restrict__ A,
    const void* __restrict__ B, float* __restrict__ Gfin,
    float* __restrict__ Gp0, const float* __restrict__ maxbuf) {
  if (maxbuf[0] < 100.f) return;    // bf16 data: handled by k_gram_mfma
  __shared__ float sL[16][68];
  __shared__ float sR[16][68];
  const int z2 = blockIdx.z;
  const int h = z2 & 1, z = z2 >> 1;
  const void *L, *Rm;
  int off;
  if (z == 0)      { L = A; Rm = A; off = 0; }
  else if (z == 1) { L = B; Rm = B; off = 262144; }
  else if (z == 2) { L = B; Rm = A; off = 524288; }
  else             { L = A; Rm = B; off = 786432; }
  float* out = (h ? Gfin : Gp0) + off;
  const int r0 = blockIdx.y * 64, c0 = blockIdx.x * 64;
  const int tx = threadIdx.x, ty = threadIdx.y;
  const int t = ty * 16 + tx;
  const int Ld = t >> 4;
  const int Lc = (t & 15) * 4;
  const int kbeg = h * 512;
  float acc[4][4] = {};
  for (int k0 = kbeg; k0 < kbeg + 512; k0 += 16) {
    *(float4*)&sL[Ld][Lc] = *(const float4*)((const float*)L +
                                             (k0 + Ld) * KA + r0 + Lc);
    *(float4*)&sR[Ld][Lc] = *(const float4*)((const float*)Rm +
                                             (k0 + Ld) * KA + c0 + Lc);
    __syncthreads();
#pragma unroll
    for (int d2 = 0; d2 < 16; ++d2) {
      const float4 av = *(const float4*)&sL[d2][ty * 4];
      const float4 bv = *(const float4*)&sR[d2][tx * 4];
      acc[0][0] = fmaf(av.x, bv.x, acc[0][0]); acc[0][1] = fmaf(av.x, bv.y, acc[0][1]);
      acc[0][2] = fmaf(av.x, bv.z, acc[0][2]); acc[0][3] = fmaf(av.x, bv.w, acc[0][3]);
      acc[1][0] = fmaf(av.y, bv.x, acc[1][0]); acc[1][1] = fmaf(av.y, bv.y, acc[1][1]);
      acc[1][2] = fmaf(av.y, bv.z, acc[1][2]); acc[1][3] = fmaf(av.y, bv.w, acc[1][3]);
      acc[2][0] = fmaf(av.z, bv.x, acc[2][0]); acc[2][1] = fmaf(av.z, bv.y, acc[2][1]);
      acc[2][2] = fmaf(av.z, bv.z, acc[2][2]); acc[2][3] = fmaf(av.z, bv.w, acc[2][3]);
      acc[3][0] = fmaf(av.w, bv.x, acc[3][0]); acc[3][1] = fmaf(av.w, bv.y, acc[3][1]);
      acc[3][2] = fmaf(av.w, bv.z, acc[3][2]); acc[3][3] = fmaf(av.w, bv.w, acc[3][3]);
    }
    __syncthreads();
  }
#pragma unroll
  for (int u = 0; u < 4; ++u) {
    const float4 o = make_float4(acc[u][0], acc[u][1], acc[u][2], acc[u][3]);
    *(float4*)(out + (r0 + ty * 4 + u) * KA + c0 + tx * 4) = o;
  }
}

// Gfin += Gp0 (f32 path only)
__global__ void k_combine(float* __restrict__ Gfin, const float* __restrict__ Gp0,
                          const float* __restrict__ maxbuf) {
  if (maxbuf[0] < 100.f) return;    // bf16 path: no partials
  const int i = blockIdx.x * 256 + threadIdx.x;
  float4* f4 = (float4*)Gfin;
  const float4 a = f4[i], b = ((const float4*)Gp0)[i];
  f4[i] = make_float4(a.x + b.x, a.y + b.y, a.z + b.z, a.w + b.w);
}

// ---------------------------------------------------------------------------
// Split G_a|G_b (first 524288 floats of Gfin) into bf16 hi+lo for the MFMA
// matvec in k_pcg. |g - hi - lo| <= 2^-17 |g|. Runs on BOTH dtype paths.
// Output into the (dead after k_combine) Gp0 region:
//   pack[0      .. 524287] = Ghi  ([Ghi_a | Ghi_b])
//   pack[524288 .. 1048575] = Glo
__global__ __launch_bounds__(256) void k_repack(const float* __restrict__ G,
    unsigned short* __restrict__ P) {
  const int i = blockIdx.x * 256 + threadIdx.x;   // 131072 threads x float4
  const float4 g = ((const float4*)G)[i];
  ushort4 h, l;
  h.x = f2bf(g.x); l.x = f2bf(g.x - bf2f(h.x));
  h.y = f2bf(g.y); l.y = f2bf(g.y - bf2f(h.y));
  h.z = f2bf(g.z); l.z = f2bf(g.z - bf2f(h.z));
  h.w = f2bf(g.w); l.w = f2bf(g.w - bf2f(h.w));
  ((ushort4*)P)[i] = h;
  ((ushort4*)(P + 524288))[i] = l;
}

// ---------------------------------------------------------------------------
// Whole PCG loop fused; matvec on the MFMA pipe. v3 (R3 counters: occupancy
// 6%, MfmaUtil 2%, dur 333us -> latency-bound): 16 waves/block (1024 thr,
// 4 waves/SIMD), each wave 2 row-tiles; explicit 1-deep software pipeline
// (next k-step's 6 frags loaded into named regs before current step's 6
// MFMAs, full unroll) to force loads in flight; wave-per-system epilogue
// (s = wv): all reductions are 6x shfl_xor within one wave, no redbuf.
// 16 systems per block, 64 blocks; G packed bf16 hi+lo (k_repack), p split
// bf16 hi+lo per iteration; 3 cross terms -> ~2e-5 relative matvec error.
// MFMA mapping per wave wv: A row-tiles at wv*32 + {0,16} (+l16),
// A[m=l16][k=quad*8+j] = G[row][k]; B[k][n=l16] = p_{sys n}[k] from pbh/pbl;
// D[row=quad*4+reg][col=l16] -> q_s[sys][row].
#define PBS 520      // p-buffer row stride in shorts (1040 B, 16B-aligned)
#define QSS 524      // q_s row stride in floats (2096 B, 16B-aligned)
#define MFMA_B16(a, bb, c) __builtin_amdgcn_mfma_f32_16x16x32_bf16(a, bb, c, 0, 0, 0)
__global__ __launch_bounds__(1024, 4) void k_pcg(
    const float* __restrict__ G_a, const float* __restrict__ G_b,
    const float* __restrict__ M, const unsigned short* __restrict__ Gpk,
    const float* __restrict__ ea, const float* __restrict__ eb,
    const float* __restrict__ smax, const float* __restrict__ maxbuf,
    void* __restrict__ out) {
  __shared__ __align__(16) float q_s[16][QSS];
  __shared__ __align__(16) unsigned short pbh[16 * PBS];
  __shared__ __align__(16) unsigned short pbl[16 * PBS];

  const int tid = threadIdx.x;
  const int b = blockIdx.x;           // 0..63
  const int rb = b * 16;              // global system base row
  const int dir = rb >> 9;
  const float* __restrict__ G = dir ? G_b : G_a;
  const unsigned short* __restrict__ Gh = Gpk + dir * 262144;
  const unsigned short* __restrict__ Gl = Gpk + 524288 + dir * 262144;

  const int lane = tid & 63, wv = tid >> 6;     // wv 0..15
  const int quad = lane >> 4, l16 = lane & 15;
  const int kq = quad * 8;
  const int rA = wv * 32 + l16;       // A-frag base row (G row index)

  const int s = wv;                   // system owned by this wave
  const int l = lane;                 // 0..63; lane owns 8 elems (2 float4)
  const int rowl = (rb + s) & (KA - 1);

  const float sm = smax[0];
  const float e1 = (dir ? ea[rowl] : eb[rowl]) / sm;
  const float q1 = 1.f / (e1 * e1 + 1.f);
  const float p1i = e1 * q1;

  float4 w4[2], di4[2], r4[2], x4[2], p4[2];
  const float* __restrict__ e2p = dir ? eb : ea;
  float rho = 0.f;
#pragma unroll
  for (int j = 0; j < 2; ++j) {
    const int c = l * 4 + 256 * j;
    const float4 e2 = *(const float4*)(e2p + c);
    const float vx = e2.x / sm, vy = e2.y / sm, vz = e2.z / sm, vw = e2.w / sm;
    const float qx = 1.f / (vx * vx + 1.f), qy = 1.f / (vy * vy + 1.f);
    const float qz = 1.f / (vz * vz + 1.f), qw = 1.f / (vw * vw + 1.f);
    float dre, dim;
    dre = p1i - vx * qx; dim = q1 - qx; w4[j].x = LMBDA_C * (dre * dre + dim * dim);
    dre = p1i - vy * qy; dim = q1 - qy; w4[j].y = LMBDA_C * (dre * dre + dim * dim);
    dre = p1i - vz * qz; dim = q1 - qz; w4[j].z = LMBDA_C * (dre * dre + dim * dim);
    dre = p1i - vw * qw; dim = q1 - qw; w4[j].w = LMBDA_C * (dre * dre + dim * dim);
    di4[j].x = 1.f / (G[(c + 0) * KA + c + 0] + w4[j].x);
    di4[j].y = 1.f / (G[(c + 1) * KA + c + 1] + w4[j].y);
    di4[j].z = 1.f / (G[(c + 2) * KA + c + 2] + w4[j].z);
    di4[j].w = 1.f / (G[(c + 3) * KA + c + 3] + w4[j].w);
    if (dir == 0) {
      r4[j] = *(const float4*)(M + rowl * KA + c);
    } else {                    // rhs = (B^T A)^T: gather M column rowl
      r4[j].x = M[(c + 0) * KA + rowl];
      r4[j].y = M[(c + 1) * KA + rowl];
      r4[j].z = M[(c + 2) * KA + rowl];
      r4[j].w = M[(c + 3) * KA + rowl];
    }
    x4[j] = make_float4(0.f, 0.f, 0.f, 0.f);
    const float4 z = make_float4(r4[j].x * di4[j].x, r4[j].y * di4[j].y,
                                 r4[j].z * di4[j].z, r4[j].w * di4[j].w);
    p4[j] = z;
    rho += r4[j].x * z.x + r4[j].y * z.y + r4[j].z * z.z + r4[j].w * z.w;
    ushort4 h4, l4;
    h4.x = f2bf(z.x); l4.x = f2bf(z.x - bf2f(h4.x));
    h4.y = f2bf(z.y); l4.y = f2bf(z.y - bf2f(h4.y));
    h4.z = f2bf(z.z); l4.z = f2bf(z.z - bf2f(h4.z));
    h4.w = f2bf(z.w); l4.w = f2bf(z.w - bf2f(h4.w));
    *(ushort4*)&pbh[s * PBS + c] = h4;
    *(ushort4*)&pbl[s * PBS + c] = l4;
  }
#pragma unroll
  for (int off = 32; off > 0; off >>= 1) rho += __shfl_xor(rho, off, 64);
  __syncthreads();                    // pbh/pbl ready for first matvec

  for (int it = 0; it < T_ITER; ++it) {
    // --- MFMA matvec: q_s[sys][row] = sum_k G[row][k] p_sys[k]
    // 1-deep software pipeline: next step's frags load during current MFMAs.
    {
      f32x4 mac0 = {0.f, 0.f, 0.f, 0.f};
      f32x4 mac1 = mac0;
      const unsigned short* __restrict__ gh0 = Gh + rA * KA + kq;
      const unsigned short* __restrict__ gl0 = Gl + rA * KA + kq;
      const unsigned short* __restrict__ gh1 = gh0 + 16 * KA;
      const unsigned short* __restrict__ gl1 = gl0 + 16 * KA;
      const unsigned short* __restrict__ pb0 = pbh + l16 * PBS + kq;
      const unsigned short* __restrict__ pb1 = pbl + l16 * PBS + kq;
      bf16x8 cah0 = *(const bf16x8*)(gh0);
      bf16x8 cal0 = *(const bf16x8*)(gl0);
      bf16x8 cah1 = *(const bf16x8*)(gh1);
      bf16x8 cal1 = *(const bf16x8*)(gl1);
      bf16x8 cbh  = *(const bf16x8*)(pb0);
      bf16x8 cbl  = *(const bf16x8*)(pb1);
#pragma unroll
      for (int ks = 0; ks < 16; ++ks) {
        const int kn = (ks + 1) * 32;
        bf16x8 nah0, nal0, nah1, nal1, nbh, nbl;
        if (ks < 15) {                // issue next-step loads first
          nah0 = *(const bf16x8*)(gh0 + kn);
          nal0 = *(const bf16x8*)(gl0 + kn);
          nah1 = *(const bf16x8*)(gh1 + kn);
          nal1 = *(const bf16x8*)(gl1 + kn);
          nbh  = *(const bf16x8*)(pb0 + kn);
          nbl  = *(const bf16x8*)(pb1 + kn);
        }
        mac0 = MFMA_B16(cah0, cbh, mac0);
        mac0 = MFMA_B16(cah0, cbl, mac0);
        mac0 = MFMA_B16(cal0, cbh, mac0);
        mac1 = MFMA_B16(cah1, cbh, mac1);
        mac1 = MFMA_B16(cah1, cbl, mac1);
        mac1 = MFMA_B16(cal1, cbh, mac1);
        if (ks < 15) {
          cah0 = nah0; cal0 = nal0; cah1 = nah1; cal1 = nal1;
          cbh = nbh; cbl = nbl;
        }
      }
      const int jb = wv * 32 + quad * 4;
      *(f32x4*)&q_s[l16][jb +  0] = mac0;
      *(f32x4*)&q_s[l16][jb + 16] = mac1;
    }
    __syncthreads();
    // --- PCG epilogue: wave s owns system s; 64-lane shfl reductions
    float pq = 0.f;
    float4 qv[2];
#pragma unroll
    for (int j = 0; j < 2; ++j) {
      const int c = l * 4 + 256 * j;
      float4 q = *(const float4*)&q_s[s][c];
      q.x += w4[j].x * p4[j].x; q.y += w4[j].y * p4[j].y;
      q.z += w4[j].z * p4[j].z; q.w += w4[j].w * p4[j].w;
      qv[j] = q;
      pq += p4[j].x * q.x + p4[j].y * q.y + p4[j].z * q.z + p4[j].w * q.w;
    }
#pragma unroll
    for (int off = 32; off > 0; off >>= 1) pq += __shfl_xor(pq, off, 64);
    const float alpha = (pq != 0.f) ? (rho / pq) : 0.f;
    float rhon = 0.f;
    float4 z4[2];
#pragma unroll
    for (int j = 0; j < 2; ++j) {
      x4[j].x = fmaf(alpha, p4[j].x, x4[j].x);
      x4[j].y = fmaf(alpha, p4[j].y, x4[j].y);
      x4[j].z = fmaf(alpha, p4[j].z, x4[j].z);
      x4[j].w = fmaf(alpha, p4[j].w, x4[j].w);
      r4[j].x = fmaf(-alpha, qv[j].x, r4[j].x);
      r4[j].y = fmaf(-alpha, qv[j].y, r4[j].y);
      r4[j].z = fmaf(-alpha, qv[j].z, r4[j].z);
      r4[j].w = fmaf(-alpha, qv[j].w, r4[j].w);
      z4[j] = make_float4(r4[j].x * di4[j].x, r4[j].y * di4[j].y,
                          r4[j].z * di4[j].z, r4[j].w * di4[j].w);
      rhon += r4[j].x * z4[j].x + r4[j].y * z4[j].y +
              r4[j].z * z4[j].z + r4[j].w * z4[j].w;
    }
#pragma unroll
    for (int off = 32; off > 0; off >>= 1) rhon += __shfl_xor(rhon, off, 64);
    const float beta = (rho != 0.f) ? (rhon / rho) : 0.f;
    rho = rhon;
#pragma unroll
    for (int j = 0; j < 2; ++j) {
      const int c = l * 4 + 256 * j;
      float4 pn;
      pn.x = fmaf(beta, p4[j].x, z4[j].x);
      pn.y = fmaf(beta, p4[j].y, z4[j].y);
      pn.z = fmaf(beta, p4[j].z, z4[j].z);
      pn.w = fmaf(beta, p4[j].w, z4[j].w);
      p4[j] = pn;
      ushort4 h4, l4;
      h4.x = f2bf(pn.x); l4.x = f2bf(pn.x - bf2f(h4.x));
      h4.y = f2bf(pn.y); l4.y = f2bf(pn.y - bf2f(h4.y));
      h4.z = f2bf(pn.z); l4.z = f2bf(pn.z - bf2f(h4.z));
      h4.w = f2bf(pn.w); l4.w = f2bf(pn.w - bf2f(h4.w));
      *(ushort4*)&pbh[s * PBS + c] = h4;
      *(ushort4*)&pbl[s * PBS + c] = l4;
    }
    __syncthreads();                  // pbh/pbl + q_s handoff for next iter
  }

  const bool isbf = (maxbuf[0] < 100.f);
#pragma unroll
  for (int j = 0; j < 2; ++j) {
    const int c = l * 4 + 256 * j;
    const int o = (rb + s) * KA + c;
    if (isbf) {
      ushort4 ob;
      ob.x = f2bf(x4[j].x); ob.y = f2bf(x4[j].y);
      ob.z = f2bf(x4[j].z); ob.w = f2bf(x4[j].w);
      *(ushort4*)((unsigned short*)out + o) = ob;
    } else {
      *(float4*)((float*)out + o) = x4[j];
    }
  }
}

// ---------------------------------------------------------------------------
extern "C" void kernel_launch(void* const* d_in, const int* in_sizes, int n_in,
                              void* d_out, int out_size, void* d_ws, size_t ws_size,
                              hipStream_t stream) {
  const void* Ain = d_in[0];   // sdescr_a [1024,512]
  const void* Bin = d_in[1];   // sdescr_b [1024,512]
  const void* Ein_a = d_in[2]; // evals_a [512]
  const void* Ein_b = d_in[3]; // evals_b [512]

  float* ws = (float*)d_ws;
  float* Gfin  = ws;              // 1048576 = [G_a | G_b | M | (f32-path A^T B)]
  float* Gp0   = Gfin + 1048576;  // 1048576 (f32-path k-half partial; then packs)
  float* eaf   = Gp0 + 1048576;   // 512
  float* ebf   = eaf + 512;       // 512
  float* maxbuf= ebf + 512;       // 1
  float* smax  = maxbuf + 1;      // 1

  float* G_a = Gfin;
  float* G_b = Gfin + 262144;
  float* M   = Gfin + 524288;
  unsigned short* Gpk = (unsigned short*)Gp0;  // [Ghi_a|Ghi_b|Glo_a|Glo_b], 2MB

  k_prep<<<1, 512, 0, stream>>>(Ain, Ein_a, Ein_b, eaf, ebf, smax, maxbuf);
  k_gram_mfma<<<dim3(8, 8, 3), 256, 0, stream>>>(Ain, Bin, Gfin, maxbuf);
  k_gram<<<dim3(8, 8, 8), dim3(16, 16), 0, stream>>>(Ain, Bin, Gfin, Gp0, maxbuf);
  k_combine<<<1024, 256, 0, stream>>>(Gfin, Gp0, maxbuf);
  k_repack<<<512, 256, 0, stream>>>(Gfin, Gpk);
  k_pcg<<<64, 1024, 0, stream>>>(G_a, G_b, M, Gpk, eaf, ebf, smax, maxbuf, d_out);
}

// Round 20
// 216.651 us; speedup vs baseline: 1.9897x; 1.9374x over previous
//
#include <hip/hip_runtime.h>
#include <hip/hip_bf16.h>

#define KA 512
#define DD 1024
#define LMBDA_C 1000.0f
#define T_ITER 11

typedef short bf16x8 __attribute__((ext_vector_type(8)));   // 8 bf16 (4 VGPRs)
typedef float f32x4 __attribute__((ext_vector_type(4)));

__device__ __forceinline__ float bf2f(unsigned short v) {
  return __uint_as_float(((unsigned)v) << 16);
}

// ---------------------------------------------------------------------------
// Fused: dtype detect (scan 8192 16-bit words of input A; f32 data decodes to
// huge bf16-interpretations w.h.p., P(miss) ~ 0.52^8192 ~ 0) + eval convert
// + joint spectral max. One block of 512.
__global__ void k_prep(const void* Ain, const void* ea_in, const void* eb_in,
                       float* eaf, float* ebf, float* smax, float* maxbuf) {
  __shared__ float red[512];
  const int t = threadIdx.x;
  const ushort4* u4 = (const ushort4*)Ain;
  float m = 0.f;
  for (int i = t; i < 2048; i += 512) {            // 8192 words
    const ushort4 v = u4[i];
    float f0 = fabsf(bf2f(v.x)), f1 = fabsf(bf2f(v.y));
    float f2 = fabsf(bf2f(v.z)), f3 = fabsf(bf2f(v.w));
    if (!isnan(f0)) m = fmaxf(m, f0);
    if (!isnan(f1)) m = fmaxf(m, f1);
    if (!isnan(f2)) m = fmaxf(m, f2);
    if (!isnan(f3)) m = fmaxf(m, f3);
  }
  red[t] = m;
  __syncthreads();
  for (int s = 256; s > 0; s >>= 1) {
    if (t < s) red[t] = fmaxf(red[t], red[t + s]);
    __syncthreads();
  }
  const float mx = red[0];
  const bool isbf = (mx < 100.f);
  if (t == 0) maxbuf[0] = mx;
  __syncthreads();
  const float a = isbf ? bf2f(((const unsigned short*)ea_in)[t])
                       : ((const float*)ea_in)[t];
  const float b = isbf ? bf2f(((const unsigned short*)eb_in)[t])
                       : ((const float*)eb_in)[t];
  eaf[t] = a;
  ebf[t] = b;
  red[t] = fmaxf(a, b);
  __syncthreads();
  for (int s = 256; s > 0; s >>= 1) {
    if (t < s) red[t] = fmaxf(red[t], red[t + s]);
    __syncthreads();
  }
  if (t == 0) smax[0] = red[0];
}

// ---------------------------------------------------------------------------
// bf16 path: MFMA gram. G = L^T * Rm via mfma_f32_16x16x32_bf16 (bf16
// products are exact in f32 — numerically equivalent to the f32 gram modulo
// sum order). Verified layouts (m89/m120): A[m=lane&15][k=quad*8+j],
// B[k=quad*8+j][n=lane&15], D[row=quad*4+reg][col=lane&15].
// 64x64 tile/block, 4 waves; wave w owns rows w*16..w*16+16 (4 col-tiles).
// LDS: k-transposed tiles (row stride 40 shorts = 80 B: 16B-aligned b128
// frag reads, conflict-free; staging writes 2-way max).
// z=0: G_a=A^T A, z=1: G_b=B^T B, z=2: M=B^T A (R_bot = M^T read by k_pcg).
#define LTS 40
__global__ __launch_bounds__(256) void k_gram_mfma(const void* __restrict__ Av,
    const void* __restrict__ Bv, float* __restrict__ Gfin,
    const float* __restrict__ maxbuf) {
  if (maxbuf[0] >= 100.f) return;   // f32 data: handled by k_gram fallback
  __shared__ __align__(16) unsigned short Lt[64][LTS];
  __shared__ __align__(16) unsigned short Bt[64][LTS];
  const int z = blockIdx.z;
  const unsigned short *L, *Rm;
  int off;
  if (z == 0)      { L = (const unsigned short*)Av; Rm = L; off = 0; }
  else if (z == 1) { L = (const unsigned short*)Bv; Rm = L; off = 262144; }
  else             { L = (const unsigned short*)Bv;
                     Rm = (const unsigned short*)Av; off = 524288; }
  float* out = Gfin + off;
  const int r0 = blockIdx.y * 64, c0 = blockIdx.x * 64;
  const int t = threadIdx.x;
  const int lane = t & 63, w = t >> 6;
  const int quad = lane >> 4, l16 = lane & 15;
  // staging map: kk = t&31 (k-row in stage), mm = (t>>5)*8 (col group)
  const int kk = t & 31;
  const int mm = (t >> 5) * 8;

  f32x4 acc0 = {0.f, 0.f, 0.f, 0.f};
  f32x4 acc1 = acc0, acc2 = acc0, acc3 = acc0;

  for (int k0 = 0; k0 < DD; k0 += 32) {
    const ushort4 la = *(const ushort4*)(L + (k0 + kk) * KA + r0 + mm);
    const ushort4 lb = *(const ushort4*)(L + (k0 + kk) * KA + r0 + mm + 4);
    const ushort4 ra = *(const ushort4*)(Rm + (k0 + kk) * KA + c0 + mm);
    const ushort4 rb = *(const ushort4*)(Rm + (k0 + kk) * KA + c0 + mm + 4);
    __syncthreads();                 // previous stage's frag reads complete
    Lt[mm + 0][kk] = la.x; Lt[mm + 1][kk] = la.y;
    Lt[mm + 2][kk] = la.z; Lt[mm + 3][kk] = la.w;
    Lt[mm + 4][kk] = lb.x; Lt[mm + 5][kk] = lb.y;
    Lt[mm + 6][kk] = lb.z; Lt[mm + 7][kk] = lb.w;
    Bt[mm + 0][kk] = ra.x; Bt[mm + 1][kk] = ra.y;
    Bt[mm + 2][kk] = ra.z; Bt[mm + 3][kk] = ra.w;
    Bt[mm + 4][kk] = rb.x; Bt[mm + 5][kk] = rb.y;
    Bt[mm + 6][kk] = rb.z; Bt[mm + 7][kk] = rb.w;
    __syncthreads();
    const bf16x8 af = *(const bf16x8*)&Lt[w * 16 + l16][quad * 8];
    const bf16x8 bf0 = *(const bf16x8*)&Bt[ 0 + l16][quad * 8];
    const bf16x8 bf1 = *(const bf16x8*)&Bt[16 + l16][quad * 8];
    const bf16x8 bf2 = *(const bf16x8*)&Bt[32 + l16][quad * 8];
    const bf16x8 bf3 = *(const bf16x8*)&Bt[48 + l16][quad * 8];
    acc0 = __builtin_amdgcn_mfma_f32_16x16x32_bf16(af, bf0, acc0, 0, 0, 0);
    acc1 = __builtin_amdgcn_mfma_f32_16x16x32_bf16(af, bf1, acc1, 0, 0, 0);
    acc2 = __builtin_amdgcn_mfma_f32_16x16x32_bf16(af, bf2, acc2, 0, 0, 0);
    acc3 = __builtin_amdgcn_mfma_f32_16x16x32_bf16(af, bf3, acc3, 0, 0, 0);
  }
  const int orow = r0 + w * 16 + quad * 4;
#pragma unroll
  for (int r = 0; r < 4; ++r) {
    float* op = out + (orow + r) * KA + c0 + l16;
    op[0]  = acc0[r];
    op[16] = acc1[r];
    op[32] = acc2[r];
    op[48] = acc3[r];
  }
}

// ---------------------------------------------------------------------------
// f32 fallback path (predicated): R12-proven 64x64 tile, k-split x2.
// z=0: G_a, z=1: G_b, z=2: M=B^T A, z=3: A^T B (unused by pcg; harmless)
__global__ __launch_bounds__(256) void k_gram(const void* __restrict__ A,
    const void* __restrict__ B, float* __restrict__ Gfin,
    float* __restrict__ Gp0, const float* __restrict__ maxbuf) {
  if (maxbuf[0] < 100.f) return;    // bf16 data: handled by k_gram_mfma
  __shared__ float sL[16][68];
  __shared__ float sR[16][68];
  const int z2 = blockIdx.z;
  const int h = z2 & 1, z = z2 >> 1;
  const void *L, *Rm;
  int off;
  if (z == 0)      { L = A; Rm = A; off = 0; }
  else if (z == 1) { L = B; Rm = B; off = 262144; }
  else if (z == 2) { L = B; Rm = A; off = 524288; }
  else             { L = A; Rm = B; off = 786432; }
  float* out = (h ? Gfin : Gp0) + off;
  const int r0 = blockIdx.y * 64, c0 = blockIdx.x * 64;
  const int tx = threadIdx.x, ty = threadIdx.y;
  const int t = ty * 16 + tx;
  const int Ld = t >> 4;
  const int Lc = (t & 15) * 4;
  const int kbeg = h * 512;
  float acc[4][4] = {};
  for (int k0 = kbeg; k0 < kbeg + 512; k0 += 16) {
    *(float4*)&sL[Ld][Lc] = *(const float4*)((const float*)L +
                                             (k0 + Ld) * KA + r0 + Lc);
    *(float4*)&sR[Ld][Lc] = *(const float4*)((const float*)Rm +
                                             (k0 + Ld) * KA + c0 + Lc);
    __syncthreads();
#pragma unroll
    for (int d2 = 0; d2 < 16; ++d2) {
      const float4 av = *(const float4*)&sL[d2][ty * 4];
      const float4 bv = *(const float4*)&sR[d2][tx * 4];
      acc[0][0] = fmaf(av.x, bv.x, acc[0][0]); acc[0][1] = fmaf(av.x, bv.y, acc[0][1]);
      acc[0][2] = fmaf(av.x, bv.z, acc[0][2]); acc[0][3] = fmaf(av.x, bv.w, acc[0][3]);
      acc[1][0] = fmaf(av.y, bv.x, acc[1][0]); acc[1][1] = fmaf(av.y, bv.y, acc[1][1]);
      acc[1][2] = fmaf(av.y, bv.z, acc[1][2]); acc[1][3] = fmaf(av.y, bv.w, acc[1][3]);
      acc[2][0] = fmaf(av.z, bv.x, acc[2][0]); acc[2][1] = fmaf(av.z, bv.y, acc[2][1]);
      acc[2][2] = fmaf(av.z, bv.z, acc[2][2]); acc[2][3] = fmaf(av.z, bv.w, acc[2][3]);
      acc[3][0] = fmaf(av.w, bv.x, acc[3][0]); acc[3][1] = fmaf(av.w, bv.y, acc[3][1]);
      acc[3][2] = fmaf(av.w, bv.z, acc[3][2]); acc[3][3] = fmaf(av.w, bv.w, acc[3][3]);
    }
    __syncthreads();
  }
#pragma unroll
  for (int u = 0; u < 4; ++u) {
    const float4 o = make_float4(acc[u][0], acc[u][1], acc[u][2], acc[u][3]);
    *(float4*)(out + (r0 + ty * 4 + u) * KA + c0 + tx * 4) = o;
  }
}

// Gfin += Gp0 (f32 path only)
__global__ void k_combine(float* __restrict__ Gfin, const float* __restrict__ Gp0,
                          const float* __restrict__ maxbuf) {
  if (maxbuf[0] < 100.f) return;    // bf16 path: no partials
  const int i = blockIdx.x * 256 + threadIdx.x;
  float4* f4 = (float4*)Gfin;
  const float4 a = f4[i], b = ((const float4*)Gp0)[i];
  f4[i] = make_float4(a.x + b.x, a.y + b.y, a.z + b.z, a.w + b.w);
}

// ---------------------------------------------------------------------------
__device__ __forceinline__ float rowreduce1(float v, float* red, int tid) {
#pragma unroll
  for (int off = 32; off > 0; off >>= 1) v += __shfl_down(v, off, 64);
  if ((tid & 63) == 0) red[tid >> 6] = v;
  __syncthreads();
  const int r = (tid >> 7) * 2;
  return red[r] + red[r + 1];
}

#define ACC16(pp, g)                                                         \
  a0.x = fmaf(p0.pp, g.x, a0.x); a0.y = fmaf(p0.pp, g.y, a0.y);              \
  a0.z = fmaf(p0.pp, g.z, a0.z); a0.w = fmaf(p0.pp, g.w, a0.w);              \
  a1.x = fmaf(p1.pp, g.x, a1.x); a1.y = fmaf(p1.pp, g.y, a1.y);              \
  a1.z = fmaf(p1.pp, g.z, a1.z); a1.w = fmaf(p1.pp, g.w, a1.w);              \
  a2.x = fmaf(p2.pp, g.x, a2.x); a2.y = fmaf(p2.pp, g.y, a2.y);              \
  a2.z = fmaf(p2.pp, g.z, a2.z); a2.w = fmaf(p2.pp, g.w, a2.w);              \
  a3.x = fmaf(p3.pp, g.x, a3.x); a3.y = fmaf(p3.pp, g.y, a3.y);              \
  a3.z = fmaf(p3.pp, g.z, a3.z); a3.w = fmaf(p3.pp, g.w, a3.w);

// Whole PCG loop fused (R13 hot loop, unchanged except rhs source):
// dir0 rhs = M[row][:] (float4); dir1 rhs = M^T -> 4 scalar gathers at init.
__global__ __launch_bounds__(512, 2) void k_pcg(
    const float* __restrict__ G_a, const float* __restrict__ G_b,
    const float* __restrict__ M, const float* __restrict__ ea,
    const float* __restrict__ eb, const float* __restrict__ smax,
    const float* __restrict__ maxbuf, void* __restrict__ out) {
  __shared__ float p_s[4][KA];
  __shared__ float qp_s[4][4][KA];
  __shared__ float redbuf[4][8];

  const int tid = threadIdx.x;
  const int b = blockIdx.x;
  const int rb = b * 4;
  const int dir = rb >> 9;
  const float* __restrict__ G = dir ? G_b : G_a;

  const int ks = tid >> 7;
  const int j0 = (tid & 127) << 2;
  const int urow = tid >> 7;
  const int uc = (tid & 127) << 2;
  const int growu = rb + urow;
  const int rowl = growu & (KA - 1);

  const float s = smax[0];
  const float e1 = (dir ? ea[rowl] : eb[rowl]) / s;
  const float q1 = 1.f / (e1 * e1 + 1.f);
  const float p1i = e1 * q1;
  float4 w4;
  {
    const float* e2p = dir ? eb : ea;
    const float4 e2 = *(const float4*)(e2p + uc);
    const float vx = e2.x / s, vy = e2.y / s, vz = e2.z / s, vw = e2.w / s;
    const float qx = 1.f / (vx * vx + 1.f), qy = 1.f / (vy * vy + 1.f);
    const float qz = 1.f / (vz * vz + 1.f), qw = 1.f / (vw * vw + 1.f);
    float dre, dim;
    dre = p1i - vx * qx; dim = q1 - qx; w4.x = LMBDA_C * (dre * dre + dim * dim);
    dre = p1i - vy * qy; dim = q1 - qy; w4.y = LMBDA_C * (dre * dre + dim * dim);
    dre = p1i - vz * qz; dim = q1 - qz; w4.z = LMBDA_C * (dre * dre + dim * dim);
    dre = p1i - vw * qw; dim = q1 - qw; w4.w = LMBDA_C * (dre * dre + dim * dim);
  }
  float4 di4;
  di4.x = 1.f / (G[(uc + 0) * KA + uc + 0] + w4.x);
  di4.y = 1.f / (G[(uc + 1) * KA + uc + 1] + w4.y);
  di4.z = 1.f / (G[(uc + 2) * KA + uc + 2] + w4.z);
  di4.w = 1.f / (G[(uc + 3) * KA + uc + 3] + w4.w);
  float4 r4;
  if (dir == 0) {
    r4 = *(const float4*)(M + growu * KA + uc);
  } else {                      // rhs = (B^T A)^T: gather M column rowl
    r4.x = M[(uc + 0) * KA + rowl];
    r4.y = M[(uc + 1) * KA + rowl];
    r4.z = M[(uc + 2) * KA + rowl];
    r4.w = M[(uc + 3) * KA + rowl];
  }
  float4 x4 = make_float4(0.f, 0.f, 0.f, 0.f);
  float4 z4 = make_float4(r4.x * di4.x, r4.y * di4.y, r4.z * di4.z, r4.w * di4.w);
  *(float4*)&p_s[urow][uc] = z4;
  float rho = rowreduce1(r4.x * z4.x + r4.y * z4.y + r4.z * z4.z + r4.w * z4.w,
                         redbuf[3], tid);

  for (int it = 0; it < T_ITER; ++it) {
    {
      float4 a0 = make_float4(0.f, 0.f, 0.f, 0.f);
      float4 a1 = a0, a2 = a0, a3 = a0;
      const int kbeg = ks << 7;
      const float* __restrict__ Gq = G + kbeg * KA + j0;
      float4 g0 = *(const float4*)(Gq + 0 * KA);
      float4 g1 = *(const float4*)(Gq + 1 * KA);
      float4 g2 = *(const float4*)(Gq + 2 * KA);
      float4 g3 = *(const float4*)(Gq + 3 * KA);
      float4 n0 = *(const float4*)(Gq + 4 * KA);
      float4 n1 = *(const float4*)(Gq + 5 * KA);
      float4 n2 = *(const float4*)(Gq + 6 * KA);
      float4 n3 = *(const float4*)(Gq + 7 * KA);
#pragma unroll 2
      for (int kc = 0; kc < 128; kc += 4) {
        const float* __restrict__ Gm = Gq + (kc + 8) * KA;
        const float4 m0 = *(const float4*)(Gm + 0 * KA);
        const float4 m1 = *(const float4*)(Gm + 1 * KA);
        const float4 m2 = *(const float4*)(Gm + 2 * KA);
        const float4 m3 = *(const float4*)(Gm + 3 * KA);
        const int k = kbeg + kc;
        const float4 p0 = *(const float4*)&p_s[0][k];
        const float4 p1 = *(const float4*)&p_s[1][k];
        const float4 p2 = *(const float4*)&p_s[2][k];
        const float4 p3 = *(const float4*)&p_s[3][k];
        ACC16(x, g0)
        ACC16(y, g1)
        ACC16(z, g2)
        ACC16(w, g3)
        g0 = n0; g1 = n1; g2 = n2; g3 = n3;
        n0 = m0; n1 = m1; n2 = m2; n3 = m3;
      }
      *(float4*)&qp_s[ks][0][j0] = a0;
      *(float4*)&qp_s[ks][1][j0] = a1;
      *(float4*)&qp_s[ks][2][j0] = a2;
      *(float4*)&qp_s[ks][3][j0] = a3;
    }
    __syncthreads();
    const float4 p4 = *(const float4*)&p_s[urow][uc];
    const float4 qa = *(const float4*)&qp_s[0][urow][uc];
    const float4 qb = *(const float4*)&qp_s[1][urow][uc];
    const float4 qc = *(const float4*)&qp_s[2][urow][uc];
    const float4 qd = *(const float4*)&qp_s[3][urow][uc];
    float4 q;
    q.x = qa.x + qb.x + qc.x + qd.x + w4.x * p4.x;
    q.y = qa.y + qb.y + qc.y + qd.y + w4.y * p4.y;
    q.z = qa.z + qb.z + qc.z + qd.z + w4.z * p4.z;
    q.w = qa.w + qb.w + qc.w + qd.w + w4.w * p4.w;
    const float pq = rowreduce1(
        p4.x * q.x + p4.y * q.y + p4.z * q.z + p4.w * q.w,
        redbuf[it & 1], tid);
    const float alpha = (pq != 0.f) ? (rho / pq) : 0.f;
    x4.x = fmaf(alpha, p4.x, x4.x); x4.y = fmaf(alpha, p4.y, x4.y);
    x4.z = fmaf(alpha, p4.z, x4.z); x4.w = fmaf(alpha, p4.w, x4.w);
    r4.x = fmaf(-alpha, q.x, r4.x); r4.y = fmaf(-alpha, q.y, r4.y);
    r4.z = fmaf(-alpha, q.z, r4.z); r4.w = fmaf(-alpha, q.w, r4.w);
    z4 = make_float4(r4.x * di4.x, r4.y * di4.y, r4.z * di4.z, r4.w * di4.w);
    const float rhon = rowreduce1(
        r4.x * z4.x + r4.y * z4.y + r4.z * z4.z + r4.w * z4.w,
        redbuf[2 + (it & 1)], tid);
    const float beta = (rho != 0.f) ? (rhon / rho) : 0.f;
    rho = rhon;
    float4 pn;
    pn.x = fmaf(beta, p4.x, z4.x); pn.y = fmaf(beta, p4.y, z4.y);
    pn.z = fmaf(beta, p4.z, z4.z); pn.w = fmaf(beta, p4.w, z4.w);
    *(float4*)&p_s[urow][uc] = pn;
    __syncthreads();
  }

  const bool isbf = (maxbuf[0] < 100.f);
  const int o = growu * KA + uc;
  if (isbf) {
    __hip_bfloat16* ob = (__hip_bfloat16*)out;
    ob[o + 0] = __float2bfloat16(x4.x);
    ob[o + 1] = __float2bfloat16(x4.y);
    ob[o + 2] = __float2bfloat16(x4.z);
    ob[o + 3] = __float2bfloat16(x4.w);
  } else {
    *(float4*)((float*)out + o) = x4;
  }
}

// ---------------------------------------------------------------------------
extern "C" void kernel_launch(void* const* d_in, const int* in_sizes, int n_in,
                              void* d_out, int out_size, void* d_ws, size_t ws_size,
                              hipStream_t stream) {
  const void* Ain = d_in[0];   // sdescr_a [1024,512]
  const void* Bin = d_in[1];   // sdescr_b [1024,512]
  const void* Ein_a = d_in[2]; // evals_a [512]
  const void* Ein_b = d_in[3]; // evals_b [512]

  float* ws = (float*)d_ws;
  float* Gfin  = ws;              // 1048576 = [G_a | G_b | M | (f32-path A^T B)]
  float* Gp0   = Gfin + 1048576;  // 1048576 (f32-path k-half partial)
  float* eaf   = Gp0 + 1048576;   // 512
  float* ebf   = eaf + 512;       // 512
  float* maxbuf= ebf + 512;       // 1
  float* smax  = maxbuf + 1;      // 1

  float* G_a = Gfin;
  float* G_b = Gfin + 262144;
  float* M   = Gfin + 524288;

  k_prep<<<1, 512, 0, stream>>>(Ain, Ein_a, Ein_b, eaf, ebf, smax, maxbuf);
  k_gram_mfma<<<dim3(8, 8, 3), 256, 0, stream>>>(Ain, Bin, Gfin, maxbuf);
  k_gram<<<dim3(8, 8, 8), dim3(16, 16), 0, stream>>>(Ain, Bin, Gfin, Gp0, maxbuf);
  k_combine<<<1024, 256, 0, stream>>>(Gfin, Gp0, maxbuf);
  k_pcg<<<256, 512, 0, stream>>>(G_a, G_b, M, eaf, ebf, smax, maxbuf, d_out);
}

// Round 23
// 214.862 us; speedup vs baseline: 2.0063x; 1.0083x over previous
//
#include <hip/hip_runtime.h>
#include <hip/hip_bf16.h>

#define KA 512
#define DD 1024
#define LMBDA_C 1000.0f
#define T_ITER 11

typedef short bf16x8 __attribute__((ext_vector_type(8)));   // 8 bf16 (4 VGPRs)
typedef float f32x4 __attribute__((ext_vector_type(4)));

__device__ __forceinline__ float bf2f(unsigned short v) {
  return __uint_as_float(((unsigned)v) << 16);
}

// ---------------------------------------------------------------------------
// Fused: dtype detect (scan 8192 16-bit words of input A; f32 data decodes to
// huge bf16-interpretations w.h.p., P(miss) ~ 0.52^8192 ~ 0) + eval convert
// + joint spectral max. One block of 512.
__global__ void k_prep(const void* Ain, const void* ea_in, const void* eb_in,
                       float* eaf, float* ebf, float* smax, float* maxbuf) {
  __shared__ float red[512];
  const int t = threadIdx.x;
  const ushort4* u4 = (const ushort4*)Ain;
  float m = 0.f;
  for (int i = t; i < 2048; i += 512) {            // 8192 words
    const ushort4 v = u4[i];
    float f0 = fabsf(bf2f(v.x)), f1 = fabsf(bf2f(v.y));
    float f2 = fabsf(bf2f(v.z)), f3 = fabsf(bf2f(v.w));
    if (!isnan(f0)) m = fmaxf(m, f0);
    if (!isnan(f1)) m = fmaxf(m, f1);
    if (!isnan(f2)) m = fmaxf(m, f2);
    if (!isnan(f3)) m = fmaxf(m, f3);
  }
  red[t] = m;
  __syncthreads();
  for (int s = 256; s > 0; s >>= 1) {
    if (t < s) red[t] = fmaxf(red[t], red[t + s]);
    __syncthreads();
  }
  const float mx = red[0];
  const bool isbf = (mx < 100.f);
  if (t == 0) maxbuf[0] = mx;
  __syncthreads();
  const float a = isbf ? bf2f(((const unsigned short*)ea_in)[t])
                       : ((const float*)ea_in)[t];
  const float b = isbf ? bf2f(((const unsigned short*)eb_in)[t])
                       : ((const float*)eb_in)[t];
  eaf[t] = a;
  ebf[t] = b;
  red[t] = fmaxf(a, b);
  __syncthreads();
  for (int s = 256; s > 0; s >>= 1) {
    if (t < s) red[t] = fmaxf(red[t], red[t + s]);
    __syncthreads();
  }
  if (t == 0) smax[0] = red[0];
}

// ---------------------------------------------------------------------------
// bf16 path: MFMA gram. G = L^T * Rm via mfma_f32_16x16x32_bf16 (bf16
// products are exact in f32 — numerically equivalent to the f32 gram modulo
// sum order). Verified layouts (m89/m120): A[m=lane&15][k=quad*8+j],
// B[k=quad*8+j][n=lane&15], D[row=quad*4+reg][col=lane&15].
// 64x64 tile/block, 4 waves; wave w owns rows w*16..w*16+16 (4 col-tiles).
// LDS: k-transposed tiles (row stride 40 shorts = 80 B: 16B-aligned b128
// frag reads, conflict-free; staging writes 2-way max).
// z=0: G_a=A^T A, z=1: G_b=B^T B, z=2: M=B^T A (R_bot = M^T read by k_pcg).
#define LTS 40
__global__ __launch_bounds__(256) void k_gram_mfma(const void* __restrict__ Av,
    const void* __restrict__ Bv, float* __restrict__ Gfin,
    const float* __restrict__ maxbuf) {
  if (maxbuf[0] >= 100.f) return;   // f32 data: handled by k_gram fallback
  __shared__ __align__(16) unsigned short Lt[64][LTS];
  __shared__ __align__(16) unsigned short Bt[64][LTS];
  const int z = blockIdx.z;
  const unsigned short *L, *Rm;
  int off;
  if (z == 0)      { L = (const unsigned short*)Av; Rm = L; off = 0; }
  else if (z == 1) { L = (const unsigned short*)Bv; Rm = L; off = 262144; }
  else             { L = (const unsigned short*)Bv;
                     Rm = (const unsigned short*)Av; off = 524288; }
  float* out = Gfin + off;
  const int r0 = blockIdx.y * 64, c0 = blockIdx.x * 64;
  const int t = threadIdx.x;
  const int lane = t & 63, w = t >> 6;
  const int quad = lane >> 4, l16 = lane & 15;
  // staging map: kk = t&31 (k-row in stage), mm = (t>>5)*8 (col group)
  const int kk = t & 31;
  const int mm = (t >> 5) * 8;

  f32x4 acc0 = {0.f, 0.f, 0.f, 0.f};
  f32x4 acc1 = acc0, acc2 = acc0, acc3 = acc0;

  for (int k0 = 0; k0 < DD; k0 += 32) {
    const ushort4 la = *(const ushort4*)(L + (k0 + kk) * KA + r0 + mm);
    const ushort4 lb = *(const ushort4*)(L + (k0 + kk) * KA + r0 + mm + 4);
    const ushort4 ra = *(const ushort4*)(Rm + (k0 + kk) * KA + c0 + mm);
    const ushort4 rb = *(const ushort4*)(Rm + (k0 + kk) * KA + c0 + mm + 4);
    __syncthreads();                 // previous stage's frag reads complete
    Lt[mm + 0][kk] = la.x; Lt[mm + 1][kk] = la.y;
    Lt[mm + 2][kk] = la.z; Lt[mm + 3][kk] = la.w;
    Lt[mm + 4][kk] = lb.x; Lt[mm + 5][kk] = lb.y;
    Lt[mm + 6][kk] = lb.z; Lt[mm + 7][kk] = lb.w;
    Bt[mm + 0][kk] = ra.x; Bt[mm + 1][kk] = ra.y;
    Bt[mm + 2][kk] = ra.z; Bt[mm + 3][kk] = ra.w;
    Bt[mm + 4][kk] = rb.x; Bt[mm + 5][kk] = rb.y;
    Bt[mm + 6][kk] = rb.z; Bt[mm + 7][kk] = rb.w;
    __syncthreads();
    const bf16x8 af = *(const bf16x8*)&Lt[w * 16 + l16][quad * 8];
    const bf16x8 bf0 = *(const bf16x8*)&Bt[ 0 + l16][quad * 8];
    const bf16x8 bf1 = *(const bf16x8*)&Bt[16 + l16][quad * 8];
    const bf16x8 bf2 = *(const bf16x8*)&Bt[32 + l16][quad * 8];
    const bf16x8 bf3 = *(const bf16x8*)&Bt[48 + l16][quad * 8];
    acc0 = __builtin_amdgcn_mfma_f32_16x16x32_bf16(af, bf0, acc0, 0, 0, 0);
    acc1 = __builtin_amdgcn_mfma_f32_16x16x32_bf16(af, bf1, acc1, 0, 0, 0);
    acc2 = __builtin_amdgcn_mfma_f32_16x16x32_bf16(af, bf2, acc2, 0, 0, 0);
    acc3 = __builtin_amdgcn_mfma_f32_16x16x32_bf16(af, bf3, acc3, 0, 0, 0);
  }
  const int orow = r0 + w * 16 + quad * 4;
#pragma unroll
  for (int r = 0; r < 4; ++r) {
    float* op = out + (orow + r) * KA + c0 + l16;
    op[0]  = acc0[r];
    op[16] = acc1[r];
    op[32] = acc2[r];
    op[48] = acc3[r];
  }
}

// ---------------------------------------------------------------------------
// f32 fallback path (predicated): R12-proven 64x64 tile, k-split x2.
// z=0: G_a, z=1: G_b, z=2: M=B^T A, z=3: A^T B (unused by pcg; harmless)
__global__ __launch_bounds__(256) void k_gram(const void* __restrict__ A,
    const void* __restrict__ B, float* __restrict__ Gfin,
    float* __restrict__ Gp0, const float* __restrict__ maxbuf) {
  if (maxbuf[0] < 100.f) return;    // bf16 data: handled by k_gram_mfma
  __shared__ float sL[16][68];
  __shared__ float sR[16][68];
  const int z2 = blockIdx.z;
  const int h = z2 & 1, z = z2 >> 1;
  const void *L, *Rm;
  int off;
  if (z == 0)      { L = A; Rm = A; off = 0; }
  else if (z == 1) { L = B; Rm = B; off = 262144; }
  else if (z == 2) { L = B; Rm = A; off = 524288; }
  else             { L = A; Rm = B; off = 786432; }
  float* out = (h ? Gfin : Gp0) + off;
  const int r0 = blockIdx.y * 64, c0 = blockIdx.x * 64;
  const int tx = threadIdx.x, ty = threadIdx.y;
  const int t = ty * 16 + tx;
  const int Ld = t >> 4;
  const int Lc = (t & 15) * 4;
  const int kbeg = h * 512;
  float acc[4][4] = {};
  for (int k0 = kbeg; k0 < kbeg + 512; k0 += 16) {
    *(float4*)&sL[Ld][Lc] = *(const float4*)((const float*)L +
                                             (k0 + Ld) * KA + r0 + Lc);
    *(float4*)&sR[Ld][Lc] = *(const float4*)((const float*)Rm +
                                             (k0 + Ld) * KA + c0 + Lc);
    __syncthreads();
#pragma unroll
    for (int d2 = 0; d2 < 16; ++d2) {
      const float4 av = *(const float4*)&sL[d2][ty * 4];
      const float4 bv = *(const float4*)&sR[d2][tx * 4];
      acc[0][0] = fmaf(av.x, bv.x, acc[0][0]); acc[0][1] = fmaf(av.x, bv.y, acc[0][1]);
      acc[0][2] = fmaf(av.x, bv.z, acc[0][2]); acc[0][3] = fmaf(av.x, bv.w, acc[0][3]);
      acc[1][0] = fmaf(av.y, bv.x, acc[1][0]); acc[1][1] = fmaf(av.y, bv.y, acc[1][1]);
      acc[1][2] = fmaf(av.y, bv.z, acc[1][2]); acc[1][3] = fmaf(av.y, bv.w, acc[1][3]);
      acc[2][0] = fmaf(av.z, bv.x, acc[2][0]); acc[2][1] = fmaf(av.z, bv.y, acc[2][1]);
      acc[2][2] = fmaf(av.z, bv.z, acc[2][2]); acc[2][3] = fmaf(av.z, bv.w, acc[2][3]);
      acc[3][0] = fmaf(av.w, bv.x, acc[3][0]); acc[3][1] = fmaf(av.w, bv.y, acc[3][1]);
      acc[3][2] = fmaf(av.w, bv.z, acc[3][2]); acc[3][3] = fmaf(av.w, bv.w, acc[3][3]);
    }
    __syncthreads();
  }
#pragma unroll
  for (int u = 0; u < 4; ++u) {
    const float4 o = make_float4(acc[u][0], acc[u][1], acc[u][2], acc[u][3]);
    *(float4*)(out + (r0 + ty * 4 + u) * KA + c0 + tx * 4) = o;
  }
}

// Gfin += Gp0 (f32 path only)
__global__ void k_combine(float* __restrict__ Gfin, const float* __restrict__ Gp0,
                          const float* __restrict__ maxbuf) {
  if (maxbuf[0] < 100.f) return;    // bf16 path: no partials
  const int i = blockIdx.x * 256 + threadIdx.x;
  float4* f4 = (float4*)Gfin;
  const float4 a = f4[i], b = ((const float4*)Gp0)[i];
  f4[i] = make_float4(a.x + b.x, a.y + b.y, a.z + b.z, a.w + b.w);
}

// ---------------------------------------------------------------------------
__device__ __forceinline__ float rowreduce1(float v, float* red, int tid) {
#pragma unroll
  for (int off = 32; off > 0; off >>= 1) v += __shfl_down(v, off, 64);
  if ((tid & 63) == 0) red[tid >> 6] = v;
  __syncthreads();
  const int r = (tid >> 7) * 2;
  return red[r] + red[r + 1];
}

#define ACC16(pp, g)                                                         \
  a0.x = fmaf(p0.pp, g.x, a0.x); a0.y = fmaf(p0.pp, g.y, a0.y);              \
  a0.z = fmaf(p0.pp, g.z, a0.z); a0.w = fmaf(p0.pp, g.w, a0.w);              \
  a1.x = fmaf(p1.pp, g.x, a1.x); a1.y = fmaf(p1.pp, g.y, a1.y);              \
  a1.z = fmaf(p1.pp, g.z, a1.z); a1.w = fmaf(p1.pp, g.w, a1.w);              \
  a2.x = fmaf(p2.pp, g.x, a2.x); a2.y = fmaf(p2.pp, g.y, a2.y);              \
  a2.z = fmaf(p2.pp, g.z, a2.z); a2.w = fmaf(p2.pp, g.w, a2.w);              \
  a3.x = fmaf(p3.pp, g.x, a3.x); a3.y = fmaf(p3.pp, g.y, a3.y);              \
  a3.z = fmaf(p3.pp, g.z, a3.z); a3.w = fmaf(p3.pp, g.w, a3.w);

// Whole PCG loop fused (R13 hot loop, unchanged except rhs source):
// dir0 rhs = M[row][:] (float4); dir1 rhs = M^T -> 4 scalar gathers at init.
// Measured R20: 131.5us, VALUBusy 42%, Occ 21% (1 block/CU), FETCH 12MB ->
// per-CU L2-ingest bound (1MB G-stream/iter/CU ~ 18.7K cyc vs 8.2K VALU).
__global__ __launch_bounds__(512, 2) void k_pcg(
    const float* __restrict__ G_a, const float* __restrict__ G_b,
    const float* __restrict__ M, const float* __restrict__ ea,
    const float* __restrict__ eb, const float* __restrict__ smax,
    const float* __restrict__ maxbuf, void* __restrict__ out) {
  __shared__ float p_s[4][KA];
  __shared__ float qp_s[4][4][KA];
  __shared__ float redbuf[4][8];

  const int tid = threadIdx.x;
  const int b = blockIdx.x;
  const int rb = b * 4;
  const int dir = rb >> 9;
  const float* __restrict__ G = dir ? G_b : G_a;

  const int ks = tid >> 7;
  const int j0 = (tid & 127) << 2;
  const int urow = tid >> 7;
  const int uc = (tid & 127) << 2;
  const int growu = rb + urow;
  const int rowl = growu & (KA - 1);

  const float s = smax[0];
  const float e1 = (dir ? ea[rowl] : eb[rowl]) / s;
  const float q1 = 1.f / (e1 * e1 + 1.f);
  const float p1i = e1 * q1;
  float4 w4;
  {
    const float* e2p = dir ? eb : ea;
    const float4 e2 = *(const float4*)(e2p + uc);
    const float vx = e2.x / s, vy = e2.y / s, vz = e2.z / s, vw = e2.w / s;
    const float qx = 1.f / (vx * vx + 1.f), qy = 1.f / (vy * vy + 1.f);
    const float qz = 1.f / (vz * vz + 1.f), qw = 1.f / (vw * vw + 1.f);
    float dre, dim;
    dre = p1i - vx * qx; dim = q1 - qx; w4.x = LMBDA_C * (dre * dre + dim * dim);
    dre = p1i - vy * qy; dim = q1 - qy; w4.y = LMBDA_C * (dre * dre + dim * dim);
    dre = p1i - vz * qz; dim = q1 - qz; w4.z = LMBDA_C * (dre * dre + dim * dim);
    dre = p1i - vw * qw; dim = q1 - qw; w4.w = LMBDA_C * (dre * dre + dim * dim);
  }
  float4 di4;
  di4.x = 1.f / (G[(uc + 0) * KA + uc + 0] + w4.x);
  di4.y = 1.f / (G[(uc + 1) * KA + uc + 1] + w4.y);
  di4.z = 1.f / (G[(uc + 2) * KA + uc + 2] + w4.z);
  di4.w = 1.f / (G[(uc + 3) * KA + uc + 3] + w4.w);
  float4 r4;
  if (dir == 0) {
    r4 = *(const float4*)(M + growu * KA + uc);
  } else {                      // rhs = (B^T A)^T: gather M column rowl
    r4.x = M[(uc + 0) * KA + rowl];
    r4.y = M[(uc + 1) * KA + rowl];
    r4.z = M[(uc + 2) * KA + rowl];
    r4.w = M[(uc + 3) * KA + rowl];
  }
  float4 x4 = make_float4(0.f, 0.f, 0.f, 0.f);
  float4 z4 = make_float4(r4.x * di4.x, r4.y * di4.y, r4.z * di4.z, r4.w * di4.w);
  *(float4*)&p_s[urow][uc] = z4;
  float rho = rowreduce1(r4.x * z4.x + r4.y * z4.y + r4.z * z4.z + r4.w * z4.w,
                         redbuf[3], tid);

  for (int it = 0; it < T_ITER; ++it) {
    {
      float4 a0 = make_float4(0.f, 0.f, 0.f, 0.f);
      float4 a1 = a0, a2 = a0, a3 = a0;
      const int kbeg = ks << 7;
      const float* __restrict__ Gq = G + kbeg * KA + j0;
      float4 g0 = *(const float4*)(Gq + 0 * KA);
      float4 g1 = *(const float4*)(Gq + 1 * KA);
      float4 g2 = *(const float4*)(Gq + 2 * KA);
      float4 g3 = *(const float4*)(Gq + 3 * KA);
      float4 n0 = *(const float4*)(Gq + 4 * KA);
      float4 n1 = *(const float4*)(Gq + 5 * KA);
      float4 n2 = *(const float4*)(Gq + 6 * KA);
      float4 n3 = *(const float4*)(Gq + 7 * KA);
#pragma unroll 2
      for (int kc = 0; kc < 128; kc += 4) {
        const float* __restrict__ Gm = Gq + (kc + 8) * KA;
        const float4 m0 = *(const float4*)(Gm + 0 * KA);
        const float4 m1 = *(const float4*)(Gm + 1 * KA);
        const float4 m2 = *(const float4*)(Gm + 2 * KA);
        const float4 m3 = *(const float4*)(Gm + 3 * KA);
        const int k = kbeg + kc;
        const float4 p0 = *(const float4*)&p_s[0][k];
        const float4 p1 = *(const float4*)&p_s[1][k];
        const float4 p2 = *(const float4*)&p_s[2][k];
        const float4 p3 = *(const float4*)&p_s[3][k];
        ACC16(x, g0)
        ACC16(y, g1)
        ACC16(z, g2)
        ACC16(w, g3)
        g0 = n0; g1 = n1; g2 = n2; g3 = n3;
        n0 = m0; n1 = m1; n2 = m2; n3 = m3;
      }
      *(float4*)&qp_s[ks][0][j0] = a0;
      *(float4*)&qp_s[ks][1][j0] = a1;
      *(float4*)&qp_s[ks][2][j0] = a2;
      *(float4*)&qp_s[ks][3][j0] = a3;
    }
    __syncthreads();
    const float4 p4 = *(const float4*)&p_s[urow][uc];
    const float4 qa = *(const float4*)&qp_s[0][urow][uc];
    const float4 qb = *(const float4*)&qp_s[1][urow][uc];
    const float4 qc = *(const float4*)&qp_s[2][urow][uc];
    const float4 qd = *(const float4*)&qp_s[3][urow][uc];
    float4 q;
    q.x = qa.x + qb.x + qc.x + qd.x + w4.x * p4.x;
    q.y = qa.y + qb.y + qc.y + qd.y + w4.y * p4.y;
    q.z = qa.z + qb.z + qc.z + qd.z + w4.z * p4.z;
    q.w = qa.w + qb.w + qc.w + qd.w + w4.w * p4.w;
    const float pq = rowreduce1(
        p4.x * q.x + p4.y * q.y + p4.z * q.z + p4.w * q.w,
        redbuf[it & 1], tid);
    const float alpha = (pq != 0.f) ? (rho / pq) : 0.f;
    x4.x = fmaf(alpha, p4.x, x4.x); x4.y = fmaf(alpha, p4.y, x4.y);
    x4.z = fmaf(alpha, p4.z, x4.z); x4.w = fmaf(alpha, p4.w, x4.w);
    r4.x = fmaf(-alpha, q.x, r4.x); r4.y = fmaf(-alpha, q.y, r4.y);
    r4.z = fmaf(-alpha, q.z, r4.z); r4.w = fmaf(-alpha, q.w, r4.w);
    z4 = make_float4(r4.x * di4.x, r4.y * di4.y, r4.z * di4.z, r4.w * di4.w);
    const float rhon = rowreduce1(
        r4.x * z4.x + r4.y * z4.y + r4.z * z4.z + r4.w * z4.w,
        redbuf[2 + (it & 1)], tid);
    const float beta = (rho != 0.f) ? (rhon / rho) : 0.f;
    rho = rhon;
    float4 pn;
    pn.x = fmaf(beta, p4.x, z4.x); pn.y = fmaf(beta, p4.y, z4.y);
    pn.z = fmaf(beta, p4.z, z4.z); pn.w = fmaf(beta, p4.w, z4.w);
    *(float4*)&p_s[urow][uc] = pn;
    __syncthreads();
  }

  const bool isbf = (maxbuf[0] < 100.f);
  const int o = growu * KA + uc;
  if (isbf) {
    __hip_bfloat16* ob = (__hip_bfloat16*)out;
    ob[o + 0] = __float2bfloat16(x4.x);
    ob[o + 1] = __float2bfloat16(x4.y);
    ob[o + 2] = __float2bfloat16(x4.z);
    ob[o + 3] = __float2bfloat16(x4.w);
  } else {
    *(float4*)((float*)out + o) = x4;
  }
}

// ---------------------------------------------------------------------------
extern "C" void kernel_launch(void* const* d_in, const int* in_sizes, int n_in,
                              void* d_out, int out_size, void* d_ws, size_t ws_size,
                              hipStream_t stream) {
  const void* Ain = d_in[0];   // sdescr_a [1024,512]
  const void* Bin = d_in[1];   // sdescr_b [1024,512]
  const void* Ein_a = d_in[2]; // evals_a [512]
  const void* Ein_b = d_in[3]; // evals_b [512]

  float* ws = (float*)d_ws;
  float* Gfin  = ws;              // 1048576 = [G_a | G_b | M | (f32-path A^T B)]
  float* Gp0   = Gfin + 1048576;  // 1048576 (f32-path k-half partial)
  float* eaf   = Gp0 + 1048576;   // 512
  float* ebf   = eaf + 512;       // 512
  float* maxbuf= ebf + 512;       // 1
  float* smax  = maxbuf + 1;      // 1

  float* G_a = Gfin;
  float* G_b = Gfin + 262144;
  float* M   = Gfin + 524288;

  k_prep<<<1, 512, 0, stream>>>(Ain, Ein_a, Ein_b, eaf, ebf, smax, maxbuf);
  k_gram_mfma<<<dim3(8, 8, 3), 256, 0, stream>>>(Ain, Bin, Gfin, maxbuf);
  k_gram<<<dim3(8, 8, 8), dim3(16, 16), 0, stream>>>(Ain, Bin, Gfin, Gp0, maxbuf);
  k_combine<<<1024, 256, 0, stream>>>(Gfin, Gp0, maxbuf);
  k_pcg<<<256, 512, 0, stream>>>(G_a, G_b, M, eaf, ebf, smax, maxbuf, d_out);
}